// Round 10
// baseline (472.372 us; speedup 1.0000x reference)
//
#include <hip/hip_runtime.h>
#include <hip/hip_bf16.h>

#define NE 64
#define HDIM 1024
#define FDIM 2048
#define TDIM 16384

typedef __attribute__((ext_vector_type(8))) short short8;
typedef __attribute__((ext_vector_type(4))) float f32x4;
typedef unsigned short u16;
typedef unsigned int u32;

struct IC0 { static constexpr int v = 0; };
struct IC1 { static constexpr int v = 1; };
template<int W> struct WN { static constexpr int v = W; };

__device__ __forceinline__ u16 f2bf(float f) {
  return __bfloat16_as_ushort(__float2bfloat16(f));
}
__device__ __forceinline__ u32 pk2(float a, float b) {
  return (u32)f2bf(a) | ((u32)f2bf(b) << 16);
}
template<int N> __device__ __forceinline__ void waitv() {
  if constexpr (N == 2)       asm volatile("s_waitcnt vmcnt(2)" ::: "memory");
  else if constexpr (N == 8)  asm volatile("s_waitcnt vmcnt(8)" ::: "memory");
  else if constexpr (N == 10) asm volatile("s_waitcnt vmcnt(10)" ::: "memory");
}
__device__ __forceinline__ void waitl() {
  asm volatile("s_waitcnt lgkmcnt(0)" ::: "memory");
}

// ---- prep: build M-block map (expert, row0, rowend), BM=256 ----
__global__ void k_prep(const int* __restrict__ tpe, int4* __restrict__ map,
                       int* __restrict__ nblocks) {
  if (threadIdx.x != 0 || blockIdx.x != 0) return;
  int off = 0, nb = 0;
  for (int e = 0; e < NE; ++e) {
    int n = tpe[e];
    for (int r = 0; r < n; r += 256) {
      int re = (r + 256 < n) ? (r + 256) : n;
      map[nb++] = make_int4(e, off + r, off + re, 0);
    }
    off += n;
  }
  *nblocks = nb;
}

// ---- f32 -> bf16 convert ----
__global__ void k_conv(const float4* __restrict__ in, uint2* __restrict__ out, int n4) {
  int stride = gridDim.x * blockDim.x;
  for (int i = blockIdx.x * blockDim.x + threadIdx.x; i < n4; i += stride) {
    float4 v = in[i];
    uint2 o;
    o.x = pk2(v.x, v.y);
    o.y = pk2(v.z, v.w);
    out[i] = o;
  }
}

// ================= GEMM1: h = gelu(x @ w1^T) =================
// 256x128 tile, BK=32, 512 thr (8 waves of 64x64). B=w1 f32 [N][K] k-contig.
// ALL staging via global_load_lds (zero staging VALU / zero ds_writes):
//   A bf16 -> sa[2] (32KB), chunk-swizzle c^((r>>1)&3) both sides.
//   B f32  -> sbf[3] (48KB), chunk-swizzle p^(nn&7) both sides; converted to
//             bf16 in-register at fragment-read time (4 pk2/frag, VALU||MFMA).
// body(t): age-ordered outstanding = B(t)[2], A(t)[2], B(t+1)[2]
//   -> vmcnt(2) drains B(t)+A(t), leaves B(t+1). UNIFORM at every t (incl. 0).
// body(t) issues A(t+1)->sa[(t+1)&1], B(t+2)->sbf[(t+2)%3]; tail clamps
// indices unconditionally (in-flight pattern invariant; round-7 fix).
template<int K, int N, int NY>
__global__ __launch_bounds__(512) void k_gemm1(
    const u16* __restrict__ A, const float* __restrict__ Bf, u16* __restrict__ C,
    const int4* __restrict__ map, const int* __restrict__ nblocks)
{
  const int mblk = (int)blockIdx.x / NY;
  const int nblk = (int)blockIdx.x % NY;
  if (mblk >= *nblocks) return;
  const int4 mi = map[mblk];
  const int e = mi.x, row0 = mi.y, rowend = mi.z;
  const int n0 = nblk << 7;
  const int NT = K / 32;

  __shared__ __align__(16) u16   sa[2][8192];   // A [256][32] bf16, swizzled
  __shared__ __align__(16) float sbf[3][4096];  // B [128][32] f32, swizzled

  const int tid = threadIdx.x;
  const int wid = tid >> 6, lane = tid & 63;
  const int wr = wid >> 1, wc = wid & 1;
  const int fr = lane & 15, fq = lane >> 4;

  f32x4 acc[4][4];
#pragma unroll
  for (int m = 0; m < 4; ++m)
#pragma unroll
    for (int n = 0; n < 4; ++n) acc[m][n] = (f32x4)0.f;

  const float* B = Bf + (size_t)e * ((size_t)N * K);

  auto issueA = [&](int t, int buf) {
#pragma unroll
    for (int i = 0; i < 2; ++i) {
      int slot = i * 512 + tid;                 // row=slot>>2, chunk=slot&3
      int r = slot >> 2, c = slot & 3;
      int cs = c ^ ((r >> 1) & 3);
      int row = row0 + r;
      row = row < TDIM ? row : TDIM - 1;
      const u16* g = A + (size_t)row * K + t * 32 + cs * 8;
      __builtin_amdgcn_global_load_lds(
          (const __attribute__((address_space(1))) u32*)g,
          (__attribute__((address_space(3))) u32*)(&sa[buf][i * 4096 + wid * 512]),
          16, 0, 0);
    }
  };
  auto issueB = [&](int t, int buf) {
#pragma unroll
    for (int i = 0; i < 2; ++i) {
      int slot = i * 512 + tid;                 // nn=slot>>3, 16B-chunk p=slot&7
      int nn = slot >> 3, p = slot & 7;
      int cs = p ^ (nn & 7);                    // pre-swizzled source chunk
      const float* g = B + (size_t)(n0 + nn) * K + t * 32 + cs * 4;
      __builtin_amdgcn_global_load_lds(
          (const __attribute__((address_space(1))) u32*)g,
          (__attribute__((address_space(3))) u32*)(&sbf[buf][i * 2048 + wid * 256]),
          16, 0, 0);
    }
  };

  auto body = [&](int t) {
    waitv<2>();                     // drains B(t)+A(t); leaves B(t+1)
    __builtin_amdgcn_s_barrier();   // all waves' tile-t staging landed
    const int curA = t & 1, curB = t % 3;
    // issue next tiles first (fly under this body's reads+MFMA)
    issueA((t + 1 < NT) ? (t + 1) : (NT - 1), curA ^ 1);
    issueB((t + 2 < NT) ? (t + 2) : (NT - 1), (t + 2) % 3);
    short8 av[4], bv[4];
#pragma unroll
    for (int m = 0; m < 4; ++m) {
      const int row = wr * 64 + m * 16 + fr;
      av[m] = *(const short8*)(&sa[curA][row * 32 + (fq ^ ((row >> 1) & 3)) * 8]);
    }
#pragma unroll
    for (int n = 0; n < 4; ++n) {
      const int nn = wc * 64 + n * 16 + fr;
      const int swz = nn & 7;
      float4 lo = *(const float4*)(&sbf[curB][nn * 32 + ((fq * 2 + 0) ^ swz) * 4]);
      float4 hi = *(const float4*)(&sbf[curB][nn * 32 + ((fq * 2 + 1) ^ swz) * 4]);
      union { short8 s; u32 u[4]; } bb;
      bb.u[0] = pk2(lo.x, lo.y); bb.u[1] = pk2(lo.z, lo.w);
      bb.u[2] = pk2(hi.x, hi.y); bb.u[3] = pk2(hi.z, hi.w);
      bv[n] = bb.s;
    }
#pragma unroll
    for (int m = 0; m < 4; ++m)
#pragma unroll
      for (int n = 0; n < 4; ++n)
        acc[m][n] = __builtin_amdgcn_mfma_f32_16x16x32_bf16(av[m], bv[n], acc[m][n], 0, 0, 0);
  };

  // prologue: queue (age order) = A(0)[2], B(0)[2], B(1)[2]
  issueA(0, 0);
  issueB(0, 0);
  issueB(1, 1);
  for (int t = 0; t < NT; ++t) body(t);

  // epilogue: gelu + bf16 store;  C/D layout row=(lane>>4)*4+j, col=lane&15
#pragma unroll
  for (int m = 0; m < 4; ++m) {
    const int rb = row0 + wr * 64 + m * 16 + fq * 4;
#pragma unroll
    for (int n = 0; n < 4; ++n) {
      const int col = n0 + wc * 64 + n * 16 + fr;
#pragma unroll
      for (int j = 0; j < 4; ++j) {
        int r = rb + j;
        if (r < rowend) {
          float vv = acc[m][n][j];
          vv = 0.5f * vv * (1.f + erff(vv * 0.70710678118654752f));
          C[(size_t)r * N + col] = f2bf(vv);
        }
      }
    }
  }
}

// ================= GEMM2: out = h @ w2  (round-9 proven path) =================
// B=w2 f32 [K][N] n-contig -> 8x f32/thread reg loads (2-3 body flight),
// cvt + transposed ds_write into 80B-pitch LDS dbuf. A: 3-rot gload_lds.
template<int K, int N, int NY>
__global__ __launch_bounds__(512) void k_gemm2(
    const u16* __restrict__ A, const float* __restrict__ Bf, float* __restrict__ C,
    const int4* __restrict__ map, const int* __restrict__ nblocks)
{
  const int mblk = (int)blockIdx.x / NY;
  const int nblk = (int)blockIdx.x % NY;
  if (mblk >= *nblocks) return;
  const int4 mi = map[mblk];
  const int e = mi.x, row0 = mi.y, rowend = mi.z;
  const int n0 = nblk << 7;
  const int NT = K / 32;
  constexpr int LB = 8;

  __shared__ __align__(16) u16 sa[3][8192];
  __shared__ __align__(16) u16 sb[2][128 * 40];

  const int tid = threadIdx.x;
  const int wid = tid >> 6, lane = tid & 63;
  const int wr = wid >> 1, wc = wid & 1;
  const int fr = lane & 15, fq = lane >> 4;

  f32x4 acc[4][4];
#pragma unroll
  for (int m = 0; m < 4; ++m)
#pragma unroll
    for (int n = 0; n < 4; ++n) acc[m][n] = (f32x4)0.f;

  const float* B = Bf + (size_t)e * ((size_t)N * K);

  float rb2[2][8];
  const int bn  = tid & 127;
  const int oct = tid >> 7;

  auto issueA = [&](int t, int buf) {
#pragma unroll
    for (int i = 0; i < 2; ++i) {
      int slot = i * 512 + tid;
      int r = slot >> 2, c = slot & 3;
      int cs = c ^ ((r >> 1) & 3);
      int row = row0 + r;
      row = row < TDIM ? row : TDIM - 1;
      const u16* g = A + (size_t)row * K + t * 32 + cs * 8;
      __builtin_amdgcn_global_load_lds(
          (const __attribute__((address_space(1))) u32*)g,
          (__attribute__((address_space(3))) u32*)(&sa[buf][i * 4096 + wid * 512]),
          16, 0, 0);
    }
  };
  auto loadB = [&](int t, auto ic) {
    constexpr int S = decltype(ic)::v;
    const float* src = B + (size_t)(t * 32 + oct * 8) * N + n0 + bn;
#pragma unroll
    for (int i = 0; i < 8; ++i) rb2[S][i] = src[(size_t)i * N];
  };
  auto writeB = [&](int buf, auto ic) {
    constexpr int S = decltype(ic)::v;
    uint4 c;
    c.x = pk2(rb2[S][0], rb2[S][1]); c.y = pk2(rb2[S][2], rb2[S][3]);
    c.z = pk2(rb2[S][4], rb2[S][5]); c.w = pk2(rb2[S][6], rb2[S][7]);
    *(uint4*)(&sb[buf][bn * 40 + oct * 8]) = c;
  };

  auto body = [&](int t, auto icCur, auto wn) {
    waitv<decltype(wn)::v>();
    waitl();
    __builtin_amdgcn_s_barrier();
    const int cur3 = t % 3, curb = t & 1, nxtb = curb ^ 1;
    short8 av[4], bv[4];
#pragma unroll
    for (int m = 0; m < 4; ++m) {
      const int row = wr * 64 + m * 16 + fr;
      av[m] = *(const short8*)(&sa[cur3][row * 32 + (fq ^ ((row >> 1) & 3)) * 8]);
    }
#pragma unroll
    for (int n = 0; n < 4; ++n)
      bv[n] = *(const short8*)(&sb[curb][(wc * 64 + n * 16 + fr) * 40 + fq * 8]);
    issueA((t + 2 < NT) ? (t + 2) : (NT - 1), (t + 2) % 3);
    writeB(nxtb, icCur);
    loadB((t + 3 < NT) ? (t + 3) : (NT - 1), icCur);
#pragma unroll
    for (int m = 0; m < 4; ++m)
#pragma unroll
      for (int n = 0; n < 4; ++n)
        acc[m][n] = __builtin_amdgcn_mfma_f32_16x16x32_bf16(av[m], bv[n], acc[m][n], 0, 0, 0);
  };

  issueA(0, 0);
  loadB(0, IC0{});
  issueA(1, 1);
  loadB(1, IC1{});
  waitv<2 + LB>();
  writeB(0, IC0{});
  loadB(2, IC0{});

  body(0, IC1{}, WN<LB>{});
  body(1, IC0{}, WN<2 + LB>{});
  for (int t = 2; t < NT; t += 2) {
    body(t,     IC1{}, WN<2 + LB>{});
    body(t + 1, IC0{}, WN<2 + LB>{});
  }

#pragma unroll
  for (int m = 0; m < 4; ++m) {
    const int rb = row0 + wr * 64 + m * 16 + fq * 4;
#pragma unroll
    for (int n = 0; n < 4; ++n) {
      const int col = n0 + wc * 64 + n * 16 + fr;
#pragma unroll
      for (int j = 0; j < 4; ++j) {
        int r = rb + j;
        if (r < rowend) C[(size_t)r * N + col] = acc[m][n][j];
      }
    }
  }
}

extern "C" void kernel_launch(void* const* d_in, const int* in_sizes, int n_in,
                              void* d_out, int out_size, void* d_ws, size_t ws_size,
                              hipStream_t stream) {
  const float* x  = (const float*)d_in[0];
  const float* w1 = (const float*)d_in[1];
  const float* w2 = (const float*)d_in[2];
  const int*  tpe = (const int*)d_in[3];

  char* ws = (char*)d_ws;
  int4* map     = (int4*)ws;
  int*  nblocks = (int*)(ws + 4096);
  u16*  xb      = (u16*)(ws + 8192);               // T*H bf16 = 32MB
  u16*  hb      = xb + (size_t)TDIM * HDIM;        // T*F bf16 = 64MB

  k_prep<<<1, 64, 0, stream>>>(tpe, map, nblocks);
  k_conv<<<2048, 256, 0, stream>>>((const float4*)x, (uint2*)xb, (TDIM * HDIM) / 4);
  // GEMM1: h = gelu(x @ w1^T)   B=w1 f32 [F][H] = [N][K], NY=16
  k_gemm1<HDIM, FDIM, 16><<<128 * 16, 512, 0, stream>>>(
      xb, w1, hb, map, nblocks);
  // GEMM2: out = h @ w2         B=w2 f32 [F][H] = [K][N], NY=8
  k_gemm2<FDIM, HDIM, 8><<<128 * 8, 512, 0, stream>>>(
      hb, w2, (float*)d_out, map, nblocks);
}